// Round 10
// baseline (52.023 us; speedup 1.0000x reference)
//
#include <hip/hip_runtime.h>

#define NPG 32
#define BUCKETS 1024  // 8 graphs per bucket
#define SEGCAP 32     // per-(block,bucket) slots; lambda=8, P(>32)~1e-12

typedef _Float16 half8 __attribute__((ext_vector_type(8)));
typedef _Float16 half4v __attribute__((ext_vector_type(4)));
typedef _Float16 half2v __attribute__((ext_vector_type(2)));
typedef float f32x4 __attribute__((ext_vector_type(4)));

#define MFMA16(a, b, c) __builtin_amdgcn_mfma_f32_16x16x32_f16(a, b, c, 0, 0, 0)

// ---------------------------------------------------------------------------
// K1: partition edges into per-(block,bucket) fixed segments — no global
// atomics, no memset. Blocks 0..27 wave 0 also prep weights (f16 hi+lo
// planes; frag duality lets one tile serve as A- or B-operand).
// packed[bucket*8192 + blk*32 + slot] (u16 payload (g&7)<<10|d<<5|s),
// fills u32-packed: fillsW[blk*256+t] = fills of buckets 4t..4t+3.
// ---------------------------------------------------------------------------
__global__ __launch_bounds__(256) void part_prep(
    const int4* __restrict__ src4, const int4* __restrict__ dst4, int E4,
    unsigned short* __restrict__ packed, unsigned* __restrict__ fillsW,
    const float* __restrict__ w0a, const float* __restrict__ w0b,
    const float* __restrict__ w1a, const float* __restrict__ w1b,
    _Float16* __restrict__ wf) {
    __shared__ unsigned cursor[BUCKETS];
    const int t = threadIdx.x;
    const int blk = blockIdx.x;
    const int b4 = blk * 2048;

    unsigned pk[32];
#pragma unroll
    for (int k = 0; k < 8; ++k) {
        int i4 = b4 + k * 256 + t;
        if (i4 < E4) {
            int4 s4 = src4[i4];
            int4 d4 = dst4[i4];
#pragma unroll
            for (int j = 0; j < 4; ++j) {
                unsigned d = (unsigned)((const int*)&d4)[j];
                unsigned s = (unsigned)((const int*)&s4)[j] & 31u;
                pk[k * 4 + j] = (d << 5) | s;  // bucket = pk>>13
            }
        } else {
#pragma unroll
            for (int j = 0; j < 4; ++j) pk[k * 4 + j] = 0xFFFFFFFFu;
        }
    }
#pragma unroll
    for (int i = 0; i < 4; ++i) cursor[i * 256 + t] = 0;
    __syncthreads();

    // ---- weight prep on blocks 0..27, wave 0 only ----
    if (blk < 28 && t < 64) {
        const float* W;
        int fi;
        if (blk < 4) {
            W = w0a; fi = blk;
        } else if (blk < 12) {
            W = w0b; fi = blk - 4;
        } else if (blk < 20) {
            W = w1a; fi = blk - 12;
        } else {
            W = w1b; fi = blk - 20;
        }
        int kt = fi >> 2, ct = fi & 3;
        int q = t >> 4, r = t & 15;
        half8 hi, lo;
#pragma unroll
        for (int j = 0; j < 8; ++j) {
            float w = W[(kt * 32 + q * 8 + j) * 64 + ct * 16 + r];
            _Float16 h = (_Float16)w;
            hi[j] = h;
            lo[j] = (_Float16)(w - (float)h);
        }
        *(half8*)(wf + blk * 1024 + t * 8) = hi;
        *(half8*)(wf + blk * 1024 + 512 + t * 8) = lo;
    }

    // ---- scatter into this block's private segments ----
#pragma unroll
    for (int k = 0; k < 32; ++k) {
        if (pk[k] == 0xFFFFFFFFu) continue;
        unsigned b = pk[k] >> 13;
        unsigned slot = atomicAdd(&cursor[b], 1u);
        if (slot < SEGCAP)
            packed[(size_t)b * 8192 + blk * SEGCAP + slot] =
                (unsigned short)(pk[k] & 0x1FFFu);
    }
    __syncthreads();
    unsigned f0 = min(cursor[4 * t + 0], (unsigned)SEGCAP);
    unsigned f1 = min(cursor[4 * t + 1], (unsigned)SEGCAP);
    unsigned f2 = min(cursor[4 * t + 2], (unsigned)SEGCAP);
    unsigned f3 = min(cursor[4 * t + 3], (unsigned)SEGCAP);
    fillsW[(size_t)blk * 256 + t] = f0 | (f1 << 8) | (f2 << 16) | (f3 << 24);
}

// ---------------------------------------------------------------------------
// K2: fused model. One block (4 waves) per 8-graph bucket. The 4KB nibble
// count array OVERLAYS wave 3's Act tail (embedding only writes bytes
// [0,4592) of each 9216B wave buffer; counts are reg-consumed before agg0's
// deeper stores, fenced by a barrier). LDS = 36864B -> 4 blocks/CU safely.
// ---------------------------------------------------------------------------
__global__ __launch_bounds__(256, 4) void seal_fused(
    const int* __restrict__ labels, const float* __restrict__ emb,
    const float* __restrict__ b0a, const float* __restrict__ b0b,
    const float* __restrict__ b1a, const float* __restrict__ b1b,
    const float* __restrict__ ws1, const float* __restrict__ bs1,
    const float* __restrict__ ws2, const float* __restrict__ bs2,
    const unsigned char* __restrict__ fills8,
    const unsigned short* __restrict__ pkd, const _Float16* __restrict__ wf,
    float* __restrict__ out) {
    const int b = blockIdx.x;  // bucket: graphs b*8 .. b*8+7
    const int tid = threadIdx.x;
    const int wid = tid >> 6, l = tid & 63;
    const int q = l >> 4, r = l & 15;

    __shared__ __align__(16) _Float16 ActAll[4][64 * 72];  // 36864 B total
    // count overlay: wave 3's Act tail, bytes [32256, 36352)
    unsigned* cntL = (unsigned*)((char*)ActAll + 32256);

#pragma unroll
    for (int i = 0; i < 4; ++i) cntL[i * 256 + tid] = 0;
    __syncthreads();

    _Float16* Act = ActAll[wid];
    const int g0 = b * 8 + wid * 2;

    // ---- count build (32B read + conditional 32B) ----
    {
        unsigned nf = fills8[(size_t)tid * 1024 + b];
        const uint4* seg4 =
            (const uint4*)(pkd + (size_t)b * 8192 + tid * SEGCAP);
        uint4 v0 = seg4[0], v1 = seg4[1];
        unsigned wds[8] = {v0.x, v0.y, v0.z, v0.w, v1.x, v1.y, v1.z, v1.w};
        int n1 = min((int)nf, 16);
#pragma unroll
        for (int i = 0; i < 16; ++i) {
            if (i < n1) {
                unsigned pk = (wds[i >> 1] >> ((i & 1) * 16)) & 0xFFFFu;
                atomicAdd(&cntL[((pk >> 10) & 7u) * 128 +
                                ((pk >> 5) & 31u) * 4 + ((pk & 31u) >> 3)],
                          1u << (4 * (pk & 7u)));
            }
        }
        if ((int)nf > 16) {
            uint4 v2 = seg4[2], v3 = seg4[3];
            unsigned wd2[8] = {v2.x, v2.y, v2.z, v2.w,
                               v3.x, v3.y, v3.z, v3.w};
#pragma unroll
            for (int i = 0; i < 16; ++i) {
                if (i + 16 < (int)nf) {
                    unsigned pk = (wd2[i >> 1] >> ((i & 1) * 16)) & 0xFFFFu;
                    atomicAdd(&cntL[((pk >> 10) & 7u) * 128 +
                                    ((pk >> 5) & 31u) * 4 + ((pk & 31u) >> 3)],
                              1u << (4 * (pk & 7u)));
                }
            }
        }
    }

    // ---- embedding -> FM0 [f][n], bytes [0,4592) of wave buffer only ----
    {
        int p = l & 31, fh = l >> 5;
        const int* lp = labels + g0 * NPG + 2 * p;
        int lab0 = min(max(lp[0], 0), 50);
        int lab1 = min(max(lp[1], 0), 50);
        float m0 = (lab0 != 0) ? 1.f : 0.f;
        float m1 = (lab1 != 0) ? 1.f : 0.f;
        const float* e0 = emb + lab0 * 32;
        const float* e1 = emb + lab1 * 32;
        half2v* A2 = (half2v*)Act;
#pragma unroll
        for (int j = 0; j < 16; ++j) {
            int f = fh * 16 + j;
            half2v v = {(_Float16)(e0[f] * m0), (_Float16)(e1[f] * m1)};
            A2[f * 36 + p] = v;
        }
    }
    __syncthreads();  // counts complete

    // ---- Cn^T B-frags from cntL (reg-consume), then fence before stores ----
    half8 cB[4];
#pragma unroll
    for (int ct = 0; ct < 4; ++ct) {
        int gg = wid * 2 + (ct >> 1);
        int d = (ct & 1) * 16 + r;
        unsigned c = cntL[gg * 128 + d * 4 + q];
        half8 f;
#pragma unroll
        for (int j = 0; j < 8; ++j) {
            int s = q * 8 + j;
            f[j] = (_Float16)((float)((c >> (4 * j)) & 15u) +
                              (s == d ? 1.f : 0.f));
        }
        cB[ct] = f;
    }
    __syncthreads();  // all waves hold cB; tail region now writable

    f32x4 acc[4][4];
    const f32x4 z4 = {0.f, 0.f, 0.f, 0.f};

    // ---- agg0: C[f32][d64] = H0^T @ Cn^T -> store RM0 [node][f32] ----
    {
        half8 aF[2][2];
#pragma unroll
        for (int mt = 0; mt < 2; ++mt)
#pragma unroll
            for (int g = 0; g < 2; ++g)
                aF[mt][g] =
                    *(const half8*)&Act[(mt * 16 + r) * 72 + g * 32 + q * 8];
#pragma unroll
        for (int mt = 0; mt < 2; ++mt)
#pragma unroll
            for (int ct = 0; ct < 4; ++ct)
                acc[mt][ct] = MFMA16(aF[mt][ct >> 1], cB[ct], z4);
#pragma unroll
        for (int mt = 0; mt < 2; ++mt)
#pragma unroll
            for (int ct = 0; ct < 4; ++ct) {
                half4v p;
#pragma unroll
                for (int i = 0; i < 4; ++i) p[i] = (_Float16)acc[mt][ct][i];
                *(half4v*)&Act[(ct * 16 + r) * 72 + mt * 16 + q * 4] = p;
            }
    }

    // ---- MLP0a: C[outf][node] = W0a^T @ act -> store RM1 [node][outf] ----
    {
        half8 bf[4];
#pragma unroll
        for (int ct = 0; ct < 4; ++ct)
            bf[ct] = *(const half8*)&Act[(ct * 16 + r) * 72 + q * 8];
        f32x4 b4[4];
#pragma unroll
        for (int mt = 0; mt < 4; ++mt)
            b4[mt] = *(const f32x4*)&b0a[mt * 16 + q * 4];
#pragma unroll
        for (int mt = 0; mt < 4; ++mt) {
            const _Float16* base = wf + (0 + mt) * 1024;
            half8 whi = *(const half8*)(base + l * 8);
            half8 wlo = *(const half8*)(base + 512 + l * 8);
#pragma unroll
            for (int ct = 0; ct < 4; ++ct) {
                f32x4 a = b4[mt];
                a = MFMA16(whi, bf[ct], a);
                a = MFMA16(wlo, bf[ct], a);
                acc[mt][ct] = a;
            }
        }
#pragma unroll
        for (int mt = 0; mt < 4; ++mt)
#pragma unroll
            for (int ct = 0; ct < 4; ++ct) {
                half4v p;
#pragma unroll
                for (int i = 0; i < 4; ++i)
                    p[i] = (_Float16)fmaxf(acc[mt][ct][i], 0.f);
                *(half4v*)&Act[(ct * 16 + r) * 72 + mt * 16 + q * 4] = p;
            }
    }

    // ---- MLP0b: C[node][outf2] = act @ W0b -> store FM1 [outf2][node] ----
    {
        half8 aA[4][2];
#pragma unroll
        for (int mt = 0; mt < 4; ++mt)
#pragma unroll
            for (int kt = 0; kt < 2; ++kt)
                aA[mt][kt] =
                    *(const half8*)&Act[(mt * 16 + r) * 72 + kt * 32 + q * 8];
#pragma unroll
        for (int ct = 0; ct < 4; ++ct) {
            float bb = b0b[ct * 16 + r];
            f32x4 a[4] = {{bb, bb, bb, bb}, {bb, bb, bb, bb},
                          {bb, bb, bb, bb}, {bb, bb, bb, bb}};
#pragma unroll
            for (int kt = 0; kt < 2; ++kt) {
                const _Float16* base = wf + (4 + kt * 4 + ct) * 1024;
                half8 whi = *(const half8*)(base + l * 8);
                half8 wlo = *(const half8*)(base + 512 + l * 8);
#pragma unroll
                for (int mt = 0; mt < 4; ++mt) {
                    a[mt] = MFMA16(aA[mt][kt], whi, a[mt]);
                    a[mt] = MFMA16(aA[mt][kt], wlo, a[mt]);
                }
            }
#pragma unroll
            for (int mt = 0; mt < 4; ++mt) acc[mt][ct] = a[mt];
        }
#pragma unroll
        for (int mt = 0; mt < 4; ++mt)
#pragma unroll
            for (int ct = 0; ct < 4; ++ct) {
                half4v p;
#pragma unroll
                for (int i = 0; i < 4; ++i)
                    p[i] = (_Float16)fmaxf(acc[mt][ct][i], 0.f);
                *(half4v*)&Act[(ct * 16 + r) * 72 + mt * 16 + q * 4] = p;
            }
    }

    // ---- agg1: C[f64][d64] = H1^T @ Cn^T -> store RM2 [node][f64] ----
    {
        half8 aF[4][2];
#pragma unroll
        for (int mt = 0; mt < 4; ++mt)
#pragma unroll
            for (int g = 0; g < 2; ++g)
                aF[mt][g] =
                    *(const half8*)&Act[(mt * 16 + r) * 72 + g * 32 + q * 8];
#pragma unroll
        for (int mt = 0; mt < 4; ++mt)
#pragma unroll
            for (int ct = 0; ct < 4; ++ct)
                acc[mt][ct] = MFMA16(aF[mt][ct >> 1], cB[ct], z4);
#pragma unroll
        for (int mt = 0; mt < 4; ++mt)
#pragma unroll
            for (int ct = 0; ct < 4; ++ct) {
                half4v p;
#pragma unroll
                for (int i = 0; i < 4; ++i) p[i] = (_Float16)acc[mt][ct][i];
                *(half4v*)&Act[(ct * 16 + r) * 72 + mt * 16 + q * 4] = p;
            }
    }

    // ---- MLP1a: C[outf][node] = W1a^T @ act -> store RM3 [node][outf] ----
    {
        half8 bf[4][2];
#pragma unroll
        for (int ct = 0; ct < 4; ++ct)
#pragma unroll
            for (int kt = 0; kt < 2; ++kt)
                bf[ct][kt] =
                    *(const half8*)&Act[(ct * 16 + r) * 72 + kt * 32 + q * 8];
        f32x4 b4[4];
#pragma unroll
        for (int mt = 0; mt < 4; ++mt)
            b4[mt] = *(const f32x4*)&b1a[mt * 16 + q * 4];
#pragma unroll
        for (int mt = 0; mt < 4; ++mt) {
            f32x4 a[4] = {b4[mt], b4[mt], b4[mt], b4[mt]};
#pragma unroll
            for (int kt = 0; kt < 2; ++kt) {
                const _Float16* base = wf + (12 + kt * 4 + mt) * 1024;
                half8 whi = *(const half8*)(base + l * 8);
                half8 wlo = *(const half8*)(base + 512 + l * 8);
#pragma unroll
                for (int ct = 0; ct < 4; ++ct) {
                    a[ct] = MFMA16(whi, bf[ct][kt], a[ct]);
                    a[ct] = MFMA16(wlo, bf[ct][kt], a[ct]);
                }
            }
#pragma unroll
            for (int ct = 0; ct < 4; ++ct) acc[mt][ct] = a[ct];
        }
#pragma unroll
        for (int mt = 0; mt < 4; ++mt)
#pragma unroll
            for (int ct = 0; ct < 4; ++ct) {
                half4v p;
#pragma unroll
                for (int i = 0; i < 4; ++i)
                    p[i] = (_Float16)fmaxf(acc[mt][ct][i], 0.f);
                *(half4v*)&Act[(ct * 16 + r) * 72 + mt * 16 + q * 4] = p;
            }
    }

    // ---- MLP1b: C[node][outf] = act @ W1b; relu + per-graph mean pool ----
    float ps[2][4];
    {
        half8 aA[4][2];
#pragma unroll
        for (int mt = 0; mt < 4; ++mt)
#pragma unroll
            for (int kt = 0; kt < 2; ++kt)
                aA[mt][kt] =
                    *(const half8*)&Act[(mt * 16 + r) * 72 + kt * 32 + q * 8];
#pragma unroll
        for (int ct = 0; ct < 4; ++ct) {
            float bb = b1b[ct * 16 + r];
            f32x4 a[4] = {{bb, bb, bb, bb}, {bb, bb, bb, bb},
                          {bb, bb, bb, bb}, {bb, bb, bb, bb}};
#pragma unroll
            for (int kt = 0; kt < 2; ++kt) {
                const _Float16* base = wf + (20 + kt * 4 + ct) * 1024;
                half8 whi = *(const half8*)(base + l * 8);
                half8 wlo = *(const half8*)(base + 512 + l * 8);
#pragma unroll
                for (int mt = 0; mt < 4; ++mt) {
                    a[mt] = MFMA16(aA[mt][kt], whi, a[mt]);
                    a[mt] = MFMA16(aA[mt][kt], wlo, a[mt]);
                }
            }
#pragma unroll
            for (int gi = 0; gi < 2; ++gi) {
                float s = 0.f;
#pragma unroll
                for (int m2 = 0; m2 < 2; ++m2)
#pragma unroll
                    for (int i = 0; i < 4; ++i)
                        s += fmaxf(a[gi * 2 + m2][i], 0.f);
                ps[gi][ct] = s;
            }
        }
    }
#pragma unroll
    for (int gi = 0; gi < 2; ++gi)
#pragma unroll
        for (int ct = 0; ct < 4; ++ct) {
            ps[gi][ct] += __shfl_xor(ps[gi][ct], 16, 64);
            ps[gi][ct] += __shfl_xor(ps[gi][ct], 32, 64);
        }
    float* F = (float*)Act;
    if (l < 16) {
#pragma unroll
        for (int gi = 0; gi < 2; ++gi)
#pragma unroll
            for (int ct = 0; ct < 4; ++ct)
                F[gi * 64 + ct * 16 + l] = ps[gi][ct] * (1.f / 32.f);
    }

    // ---- scorer: relu(hg @ ws1 + bs1) @ ws2 + bs2 (fp32, both graphs) ----
    float a0 = bs1[l], a1 = a0;
#pragma unroll
    for (int kq = 0; kq < 16; ++kq) {
        f32x4 f0 = *(const f32x4*)&F[kq * 4];
        f32x4 f1 = *(const f32x4*)&F[64 + kq * 4];
#pragma unroll
        for (int j = 0; j < 4; ++j) {
            float wv = ws1[(kq * 4 + j) * 64 + l];
            a0 = fmaf(f0[j], wv, a0);
            a1 = fmaf(f1[j], wv, a1);
        }
    }
    float w2 = ws2[l];
    float p0 = fmaxf(a0, 0.f) * w2;
    float p1 = fmaxf(a1, 0.f) * w2;
#pragma unroll
    for (int off = 32; off > 0; off >>= 1) {
        p0 += __shfl_xor(p0, off, 64);
        p1 += __shfl_xor(p1, off, 64);
    }
    if (l == 0) {
        float bb = bs2[0];
        out[g0] = p0 + bb;
        out[g0 + 1] = p1 + bb;
    }
}

// ---------------------------------------------------------------------------
extern "C" void kernel_launch(void* const* d_in, const int* in_sizes, int n_in,
                              void* d_out, int out_size, void* d_ws,
                              size_t ws_size, hipStream_t stream) {
    const int* labels = (const int*)d_in[0];
    const int* src = (const int*)d_in[1];
    const int* dst = (const int*)d_in[2];
    const float* emb = (const float*)d_in[4];
    const float* w0a = (const float*)d_in[5];
    const float* b0a = (const float*)d_in[6];
    const float* w0b = (const float*)d_in[7];
    const float* b0b = (const float*)d_in[8];
    const float* w1a = (const float*)d_in[9];
    const float* b1a = (const float*)d_in[10];
    const float* w1b = (const float*)d_in[11];
    const float* b1b = (const float*)d_in[12];
    const float* ws1 = (const float*)d_in[13];
    const float* bs1 = (const float*)d_in[14];
    const float* ws2 = (const float*)d_in[15];
    const float* bs2 = (const float*)d_in[16];
    float* out = (float*)d_out;

    const int E = in_sizes[1];  // 2097152 edges
    const int Gn = out_size;    // 8192 subgraphs

    // ws layout: wf (57344 B) | pad | packed (16 MB @ 65536) | fills (256 KB)
    _Float16* wf = (_Float16*)d_ws;
    unsigned short* packed = (unsigned short*)((char*)d_ws + 65536);
    unsigned* fillsW = (unsigned*)((char*)d_ws + 65536 + 16777216);

    const int E4 = E / 4;
    part_prep<<<(E4 + 2047) / 2048, 256, 0, stream>>>(
        (const int4*)src, (const int4*)dst, E4, packed, fillsW, w0a, w0b, w1a,
        w1b, wf);
    seal_fused<<<Gn / 8, 256, 0, stream>>>(
        labels, emb, b0a, b0b, b1a, b1b, ws1, bs1, ws2, bs2,
        (const unsigned char*)fillsW, packed, wf, out);
}

// Round 11
// 51.748 us; speedup vs baseline: 1.0053x; 1.0053x over previous
//
#include <hip/hip_runtime.h>

#define NPG 32
#define BUCKETS 1024  // 8 graphs per bucket
#define BPP 512       // buckets per staging pass

typedef _Float16 half8 __attribute__((ext_vector_type(8)));
typedef _Float16 half4v __attribute__((ext_vector_type(4)));
typedef _Float16 half2v __attribute__((ext_vector_type(2)));
typedef float f32x4 __attribute__((ext_vector_type(4)));

#define MFMA16(a, b, c) __builtin_amdgcn_mfma_f32_16x16x32_f16(a, b, c, 0, 0, 0)

// ---------------------------------------------------------------------------
// K1: partition 8192 edges/block into per-(block,bucket) 64B segments, staged
// in LDS (2 passes x 512 buckets) and written out COALESCED. Segment layout
// (32 u16): slot0 = count, slots 1..31 = edges ((g&7)<<10|d<<5|s). Global
// layout is block-major: packed[blk*32768 + bucket*32] u16 — each segment is
// read exactly once by seal_fused. No global atomics, no fills array.
// Blocks 0..27 wave 0 also prep f16 hi+lo weight planes (frag duality).
// ---------------------------------------------------------------------------
__global__ __launch_bounds__(256) void part_prep(
    const int4* __restrict__ src4, const int4* __restrict__ dst4, int E4,
    unsigned short* __restrict__ packed,
    const float* __restrict__ w0a, const float* __restrict__ w0b,
    const float* __restrict__ w1a, const float* __restrict__ w1b,
    _Float16* __restrict__ wf) {
    __shared__ unsigned cur[BPP];              // 2 KB
    __shared__ unsigned short segL[BPP * 32];  // 32 KB
    const int t = threadIdx.x;
    const int blk = blockIdx.x;
    const int b4 = blk * 2048;

    unsigned pk[32];
#pragma unroll
    for (int k = 0; k < 8; ++k) {
        int i4 = b4 + k * 256 + t;
        if (i4 < E4) {
            int4 s4 = src4[i4];
            int4 d4 = dst4[i4];
#pragma unroll
            for (int j = 0; j < 4; ++j) {
                unsigned d = (unsigned)((const int*)&d4)[j];
                unsigned s = (unsigned)((const int*)&s4)[j] & 31u;
                pk[k * 4 + j] = (d << 5) | s;  // bucket = pk>>13
            }
        } else {
#pragma unroll
            for (int j = 0; j < 4; ++j) pk[k * 4 + j] = 0xFFFFFFFFu;
        }
    }

    // ---- weight prep on blocks 0..27, wave 0 only (between barriers) ----
    if (blk < 28 && t < 64) {
        const float* W;
        int fi;
        if (blk < 4) {
            W = w0a; fi = blk;
        } else if (blk < 12) {
            W = w0b; fi = blk - 4;
        } else if (blk < 20) {
            W = w1a; fi = blk - 12;
        } else {
            W = w1b; fi = blk - 20;
        }
        int kt = fi >> 2, ct = fi & 3;
        int q = t >> 4, r = t & 15;
        half8 hi, lo;
#pragma unroll
        for (int j = 0; j < 8; ++j) {
            float w = W[(kt * 32 + q * 8 + j) * 64 + ct * 16 + r];
            _Float16 h = (_Float16)w;
            hi[j] = h;
            lo[j] = (_Float16)(w - (float)h);
        }
        *(half8*)(wf + blk * 1024 + t * 8) = hi;
        *(half8*)(wf + blk * 1024 + 512 + t * 8) = lo;
    }

    // ---- two staging passes over bucket halves ----
    for (int p = 0; p < 2; ++p) {
        cur[t] = 0;
        cur[256 + t] = 0;
        __syncthreads();
#pragma unroll
        for (int k = 0; k < 32; ++k) {
            unsigned v = pk[k];
            if (v == 0xFFFFFFFFu) continue;
            unsigned bkt = v >> 13;
            if ((int)(bkt >> 9) != p) continue;
            unsigned lb = bkt & 511u;
            unsigned slot = atomicAdd(&cur[lb], 1u);
            if (slot < 31u)
                segL[lb * 32 + 1 + slot] = (unsigned short)(v & 0x1FFFu);
        }
        __syncthreads();
        // counts into slot 0 (same thread later reads them), coalesced burst
#pragma unroll
        for (int j = 0; j < 2; ++j) {
            int lb = j * 256 + t;
            segL[lb * 32] = (unsigned short)min(cur[lb], 31u);
            const uint4* ls = (const uint4*)&segL[lb * 32];
            uint4 u0 = ls[0], u1 = ls[1], u2 = ls[2], u3 = ls[3];
            uint4* gs = (uint4*)(packed + (size_t)blk * 32768 +
                                 (size_t)(p * BPP + lb) * 32);
            gs[0] = u0;
            gs[1] = u1;
            gs[2] = u2;
            gs[3] = u3;
        }
        __syncthreads();
    }
}

// ---------------------------------------------------------------------------
// K2: fused model. One block (4 waves) per 8-graph bucket. Thread tid reads
// partition-block tid's segment for this bucket (32B, + conditional 32B when
// count>15; count embedded in slot 0). Counts -> nibble array overlaying
// wave 3's Act tail (reg-consumed, barrier-fenced). LDS 36864B -> 4 blk/CU.
// ---------------------------------------------------------------------------
__global__ __launch_bounds__(256, 4) void seal_fused(
    const int* __restrict__ labels, const float* __restrict__ emb,
    const float* __restrict__ b0a, const float* __restrict__ b0b,
    const float* __restrict__ b1a, const float* __restrict__ b1b,
    const float* __restrict__ ws1, const float* __restrict__ bs1,
    const float* __restrict__ ws2, const float* __restrict__ bs2,
    const unsigned short* __restrict__ pkd, int nPart,
    const _Float16* __restrict__ wf, float* __restrict__ out) {
    const int b = blockIdx.x;  // bucket: graphs b*8 .. b*8+7
    const int tid = threadIdx.x;
    const int wid = tid >> 6, l = tid & 63;
    const int q = l >> 4, r = l & 15;

    __shared__ __align__(16) _Float16 ActAll[4][64 * 72];  // 36864 B total
    unsigned* cntL = (unsigned*)((char*)ActAll + 32256);   // overlay, 4 KB

#pragma unroll
    for (int i = 0; i < 4; ++i) cntL[i * 256 + tid] = 0;
    __syncthreads();

    _Float16* Act = ActAll[wid];
    const int g0 = b * 8 + wid * 2;

    // ---- count build from embedded-count segments ----
    if (tid < nPart) {
        const uint4* seg4 =
            (const uint4*)(pkd + (size_t)tid * 32768 + (size_t)b * 32);
        uint4 v0 = seg4[0], v1 = seg4[1];
        unsigned w01[8] = {v0.x, v0.y, v0.z, v0.w, v1.x, v1.y, v1.z, v1.w};
        unsigned nf = w01[0] & 0xFFFFu;  // slot 0 = count (<=31 by writer)
#pragma unroll
        for (int i = 1; i <= 15; ++i) {
            if ((unsigned)i <= nf) {
                unsigned pk = (w01[i >> 1] >> ((i & 1) * 16)) & 0xFFFFu;
                atomicAdd(&cntL[((pk >> 10) & 7u) * 128 +
                                ((pk >> 5) & 31u) * 4 + ((pk & 31u) >> 3)],
                          1u << (4 * (pk & 7u)));
            }
        }
        if (nf > 15u) {
            uint4 v2 = seg4[2], v3 = seg4[3];
            unsigned w23[8] = {v2.x, v2.y, v2.z, v2.w,
                               v3.x, v3.y, v3.z, v3.w};
#pragma unroll
            for (int i = 16; i <= 31; ++i) {
                if ((unsigned)i <= nf) {
                    unsigned pk =
                        (w23[(i - 16) >> 1] >> ((i & 1) * 16)) & 0xFFFFu;
                    atomicAdd(&cntL[((pk >> 10) & 7u) * 128 +
                                    ((pk >> 5) & 31u) * 4 + ((pk & 31u) >> 3)],
                              1u << (4 * (pk & 7u)));
                }
            }
        }
    }

    // ---- embedding -> FM0 [f][n], bytes [0,4592) of wave buffer only ----
    {
        int p = l & 31, fh = l >> 5;
        const int* lp = labels + g0 * NPG + 2 * p;
        int lab0 = min(max(lp[0], 0), 50);
        int lab1 = min(max(lp[1], 0), 50);
        float m0 = (lab0 != 0) ? 1.f : 0.f;
        float m1 = (lab1 != 0) ? 1.f : 0.f;
        const float* e0 = emb + lab0 * 32;
        const float* e1 = emb + lab1 * 32;
        half2v* A2 = (half2v*)Act;
#pragma unroll
        for (int j = 0; j < 16; ++j) {
            int f = fh * 16 + j;
            half2v v = {(_Float16)(e0[f] * m0), (_Float16)(e1[f] * m1)};
            A2[f * 36 + p] = v;
        }
    }
    __syncthreads();  // counts complete

    // ---- Cn^T B-frags from cntL (reg-consume), then fence before stores ----
    half8 cB[4];
#pragma unroll
    for (int ct = 0; ct < 4; ++ct) {
        int gg = wid * 2 + (ct >> 1);
        int d = (ct & 1) * 16 + r;
        unsigned c = cntL[gg * 128 + d * 4 + q];
        half8 f;
#pragma unroll
        for (int j = 0; j < 8; ++j) {
            int s = q * 8 + j;
            f[j] = (_Float16)((float)((c >> (4 * j)) & 15u) +
                              (s == d ? 1.f : 0.f));
        }
        cB[ct] = f;
    }
    __syncthreads();  // all waves hold cB; tail region now writable

    f32x4 acc[4][4];
    const f32x4 z4 = {0.f, 0.f, 0.f, 0.f};

    // ---- agg0: C[f32][d64] = H0^T @ Cn^T -> store RM0 [node][f32] ----
    {
        half8 aF[2][2];
#pragma unroll
        for (int mt = 0; mt < 2; ++mt)
#pragma unroll
            for (int g = 0; g < 2; ++g)
                aF[mt][g] =
                    *(const half8*)&Act[(mt * 16 + r) * 72 + g * 32 + q * 8];
#pragma unroll
        for (int mt = 0; mt < 2; ++mt)
#pragma unroll
            for (int ct = 0; ct < 4; ++ct)
                acc[mt][ct] = MFMA16(aF[mt][ct >> 1], cB[ct], z4);
#pragma unroll
        for (int mt = 0; mt < 2; ++mt)
#pragma unroll
            for (int ct = 0; ct < 4; ++ct) {
                half4v p;
#pragma unroll
                for (int i = 0; i < 4; ++i) p[i] = (_Float16)acc[mt][ct][i];
                *(half4v*)&Act[(ct * 16 + r) * 72 + mt * 16 + q * 4] = p;
            }
    }

    // ---- MLP0a: C[outf][node] = W0a^T @ act -> store RM1 [node][outf] ----
    {
        half8 bf[4];
#pragma unroll
        for (int ct = 0; ct < 4; ++ct)
            bf[ct] = *(const half8*)&Act[(ct * 16 + r) * 72 + q * 8];
        f32x4 b4[4];
#pragma unroll
        for (int mt = 0; mt < 4; ++mt)
            b4[mt] = *(const f32x4*)&b0a[mt * 16 + q * 4];
#pragma unroll
        for (int mt = 0; mt < 4; ++mt) {
            const _Float16* base = wf + (0 + mt) * 1024;
            half8 whi = *(const half8*)(base + l * 8);
            half8 wlo = *(const half8*)(base + 512 + l * 8);
#pragma unroll
            for (int ct = 0; ct < 4; ++ct) {
                f32x4 a = b4[mt];
                a = MFMA16(whi, bf[ct], a);
                a = MFMA16(wlo, bf[ct], a);
                acc[mt][ct] = a;
            }
        }
#pragma unroll
        for (int mt = 0; mt < 4; ++mt)
#pragma unroll
            for (int ct = 0; ct < 4; ++ct) {
                half4v p;
#pragma unroll
                for (int i = 0; i < 4; ++i)
                    p[i] = (_Float16)fmaxf(acc[mt][ct][i], 0.f);
                *(half4v*)&Act[(ct * 16 + r) * 72 + mt * 16 + q * 4] = p;
            }
    }

    // ---- MLP0b: C[node][outf2] = act @ W0b -> store FM1 [outf2][node] ----
    {
        half8 aA[4][2];
#pragma unroll
        for (int mt = 0; mt < 4; ++mt)
#pragma unroll
            for (int kt = 0; kt < 2; ++kt)
                aA[mt][kt] =
                    *(const half8*)&Act[(mt * 16 + r) * 72 + kt * 32 + q * 8];
#pragma unroll
        for (int ct = 0; ct < 4; ++ct) {
            float bb = b0b[ct * 16 + r];
            f32x4 a[4] = {{bb, bb, bb, bb}, {bb, bb, bb, bb},
                          {bb, bb, bb, bb}, {bb, bb, bb, bb}};
#pragma unroll
            for (int kt = 0; kt < 2; ++kt) {
                const _Float16* base = wf + (4 + kt * 4 + ct) * 1024;
                half8 whi = *(const half8*)(base + l * 8);
                half8 wlo = *(const half8*)(base + 512 + l * 8);
#pragma unroll
                for (int mt = 0; mt < 4; ++mt) {
                    a[mt] = MFMA16(aA[mt][kt], whi, a[mt]);
                    a[mt] = MFMA16(aA[mt][kt], wlo, a[mt]);
                }
            }
#pragma unroll
            for (int mt = 0; mt < 4; ++mt) acc[mt][ct] = a[mt];
        }
#pragma unroll
        for (int mt = 0; mt < 4; ++mt)
#pragma unroll
            for (int ct = 0; ct < 4; ++ct) {
                half4v p;
#pragma unroll
                for (int i = 0; i < 4; ++i)
                    p[i] = (_Float16)fmaxf(acc[mt][ct][i], 0.f);
                *(half4v*)&Act[(ct * 16 + r) * 72 + mt * 16 + q * 4] = p;
            }
    }

    // ---- agg1: C[f64][d64] = H1^T @ Cn^T -> store RM2 [node][f64] ----
    {
        half8 aF[4][2];
#pragma unroll
        for (int mt = 0; mt < 4; ++mt)
#pragma unroll
            for (int g = 0; g < 2; ++g)
                aF[mt][g] =
                    *(const half8*)&Act[(mt * 16 + r) * 72 + g * 32 + q * 8];
#pragma unroll
        for (int mt = 0; mt < 4; ++mt)
#pragma unroll
            for (int ct = 0; ct < 4; ++ct)
                acc[mt][ct] = MFMA16(aF[mt][ct >> 1], cB[ct], z4);
#pragma unroll
        for (int mt = 0; mt < 4; ++mt)
#pragma unroll
            for (int ct = 0; ct < 4; ++ct) {
                half4v p;
#pragma unroll
                for (int i = 0; i < 4; ++i) p[i] = (_Float16)acc[mt][ct][i];
                *(half4v*)&Act[(ct * 16 + r) * 72 + mt * 16 + q * 4] = p;
            }
    }

    // ---- MLP1a: C[outf][node] = W1a^T @ act -> store RM3 [node][outf] ----
    {
        half8 bf[4][2];
#pragma unroll
        for (int ct = 0; ct < 4; ++ct)
#pragma unroll
            for (int kt = 0; kt < 2; ++kt)
                bf[ct][kt] =
                    *(const half8*)&Act[(ct * 16 + r) * 72 + kt * 32 + q * 8];
        f32x4 b4[4];
#pragma unroll
        for (int mt = 0; mt < 4; ++mt)
            b4[mt] = *(const f32x4*)&b1a[mt * 16 + q * 4];
#pragma unroll
        for (int mt = 0; mt < 4; ++mt) {
            f32x4 a[4] = {b4[mt], b4[mt], b4[mt], b4[mt]};
#pragma unroll
            for (int kt = 0; kt < 2; ++kt) {
                const _Float16* base = wf + (12 + kt * 4 + mt) * 1024;
                half8 whi = *(const half8*)(base + l * 8);
                half8 wlo = *(const half8*)(base + 512 + l * 8);
#pragma unroll
                for (int ct = 0; ct < 4; ++ct) {
                    a[ct] = MFMA16(whi, bf[ct][kt], a[ct]);
                    a[ct] = MFMA16(wlo, bf[ct][kt], a[ct]);
                }
            }
#pragma unroll
            for (int ct = 0; ct < 4; ++ct) acc[mt][ct] = a[ct];
        }
#pragma unroll
        for (int mt = 0; mt < 4; ++mt)
#pragma unroll
            for (int ct = 0; ct < 4; ++ct) {
                half4v p;
#pragma unroll
                for (int i = 0; i < 4; ++i)
                    p[i] = (_Float16)fmaxf(acc[mt][ct][i], 0.f);
                *(half4v*)&Act[(ct * 16 + r) * 72 + mt * 16 + q * 4] = p;
            }
    }

    // ---- MLP1b: C[node][outf] = act @ W1b; relu + per-graph mean pool ----
    float ps[2][4];
    {
        half8 aA[4][2];
#pragma unroll
        for (int mt = 0; mt < 4; ++mt)
#pragma unroll
            for (int kt = 0; kt < 2; ++kt)
                aA[mt][kt] =
                    *(const half8*)&Act[(mt * 16 + r) * 72 + kt * 32 + q * 8];
#pragma unroll
        for (int ct = 0; ct < 4; ++ct) {
            float bb = b1b[ct * 16 + r];
            f32x4 a[4] = {{bb, bb, bb, bb}, {bb, bb, bb, bb},
                          {bb, bb, bb, bb}, {bb, bb, bb, bb}};
#pragma unroll
            for (int kt = 0; kt < 2; ++kt) {
                const _Float16* base = wf + (20 + kt * 4 + ct) * 1024;
                half8 whi = *(const half8*)(base + l * 8);
                half8 wlo = *(const half8*)(base + 512 + l * 8);
#pragma unroll
                for (int mt = 0; mt < 4; ++mt) {
                    a[mt] = MFMA16(aA[mt][kt], whi, a[mt]);
                    a[mt] = MFMA16(aA[mt][kt], wlo, a[mt]);
                }
            }
#pragma unroll
            for (int gi = 0; gi < 2; ++gi) {
                float s = 0.f;
#pragma unroll
                for (int m2 = 0; m2 < 2; ++m2)
#pragma unroll
                    for (int i = 0; i < 4; ++i)
                        s += fmaxf(a[gi * 2 + m2][i], 0.f);
                ps[gi][ct] = s;
            }
        }
    }
#pragma unroll
    for (int gi = 0; gi < 2; ++gi)
#pragma unroll
        for (int ct = 0; ct < 4; ++ct) {
            ps[gi][ct] += __shfl_xor(ps[gi][ct], 16, 64);
            ps[gi][ct] += __shfl_xor(ps[gi][ct], 32, 64);
        }
    float* F = (float*)Act;
    if (l < 16) {
#pragma unroll
        for (int gi = 0; gi < 2; ++gi)
#pragma unroll
            for (int ct = 0; ct < 4; ++ct)
                F[gi * 64 + ct * 16 + l] = ps[gi][ct] * (1.f / 32.f);
    }

    // ---- scorer: relu(hg @ ws1 + bs1) @ ws2 + bs2 (fp32, both graphs) ----
    float a0 = bs1[l], a1 = a0;
#pragma unroll
    for (int kq = 0; kq < 16; ++kq) {
        f32x4 f0 = *(const f32x4*)&F[kq * 4];
        f32x4 f1 = *(const f32x4*)&F[64 + kq * 4];
#pragma unroll
        for (int j = 0; j < 4; ++j) {
            float wv = ws1[(kq * 4 + j) * 64 + l];
            a0 = fmaf(f0[j], wv, a0);
            a1 = fmaf(f1[j], wv, a1);
        }
    }
    float w2 = ws2[l];
    float p0 = fmaxf(a0, 0.f) * w2;
    float p1 = fmaxf(a1, 0.f) * w2;
#pragma unroll
    for (int off = 32; off > 0; off >>= 1) {
        p0 += __shfl_xor(p0, off, 64);
        p1 += __shfl_xor(p1, off, 64);
    }
    if (l == 0) {
        float bb = bs2[0];
        out[g0] = p0 + bb;
        out[g0 + 1] = p1 + bb;
    }
}

// ---------------------------------------------------------------------------
extern "C" void kernel_launch(void* const* d_in, const int* in_sizes, int n_in,
                              void* d_out, int out_size, void* d_ws,
                              size_t ws_size, hipStream_t stream) {
    const int* labels = (const int*)d_in[0];
    const int* src = (const int*)d_in[1];
    const int* dst = (const int*)d_in[2];
    const float* emb = (const float*)d_in[4];
    const float* w0a = (const float*)d_in[5];
    const float* b0a = (const float*)d_in[6];
    const float* w0b = (const float*)d_in[7];
    const float* b0b = (const float*)d_in[8];
    const float* w1a = (const float*)d_in[9];
    const float* b1a = (const float*)d_in[10];
    const float* w1b = (const float*)d_in[11];
    const float* b1b = (const float*)d_in[12];
    const float* ws1 = (const float*)d_in[13];
    const float* bs1 = (const float*)d_in[14];
    const float* ws2 = (const float*)d_in[15];
    const float* bs2 = (const float*)d_in[16];
    float* out = (float*)d_out;

    const int E = in_sizes[1];  // 2097152 edges
    const int Gn = out_size;    // 8192 subgraphs

    // ws layout: wf (57344 B, pad to 64 KB) | packed (nPart * 64 KB)
    _Float16* wf = (_Float16*)d_ws;
    unsigned short* packed = (unsigned short*)((char*)d_ws + 65536);

    const int E4 = E / 4;
    const int nPart = (E4 + 2047) / 2048;  // 256 for E=2M
    part_prep<<<nPart, 256, 0, stream>>>((const int4*)src, (const int4*)dst,
                                         E4, packed, w0a, w0b, w1a, w1b, wf);
    seal_fused<<<Gn / 8, 256, 0, stream>>>(labels, emb, b0a, b0b, b1a, b1b,
                                           ws1, bs1, ws2, bs2, packed, nPart,
                                           wf, out);
}

// Round 12
// 47.445 us; speedup vs baseline: 1.0965x; 1.0907x over previous
//
#include <hip/hip_runtime.h>

#define NPG 32
#define BUCKETS 1024  // 8 graphs per bucket
#define BPP 512       // buckets per staging pass

typedef _Float16 half8 __attribute__((ext_vector_type(8)));
typedef _Float16 half4v __attribute__((ext_vector_type(4)));
typedef _Float16 half2v __attribute__((ext_vector_type(2)));
typedef float f32x4 __attribute__((ext_vector_type(4)));

#define MFMA16(a, b, c) __builtin_amdgcn_mfma_f32_16x16x32_f16(a, b, c, 0, 0, 0)

// ---------------------------------------------------------------------------
// K1: partition 8192 edges/block into per-(block,bucket) 64B segments, staged
// in LDS (2 passes x 512 buckets) and written out COALESCED. Segment layout
// (32 u16): slot0 = count, slots 1..31 = edges ((g&7)<<10|d<<5|s). Global
// layout is block-major: packed[blk*32768 + bucket*32] u16 — each segment is
// read exactly once by seal_fused. No global atomics, no fills array.
// Blocks 0..27 wave 0 also prep f16 weight planes (hi used; lo kept in
// layout for compat but no longer consumed — R12 dropped lo MFMAs).
// ---------------------------------------------------------------------------
__global__ __launch_bounds__(256) void part_prep(
    const int4* __restrict__ src4, const int4* __restrict__ dst4, int E4,
    unsigned short* __restrict__ packed,
    const float* __restrict__ w0a, const float* __restrict__ w0b,
    const float* __restrict__ w1a, const float* __restrict__ w1b,
    _Float16* __restrict__ wf) {
    __shared__ unsigned cur[BPP];              // 2 KB
    __shared__ unsigned short segL[BPP * 32];  // 32 KB
    const int t = threadIdx.x;
    const int blk = blockIdx.x;
    const int b4 = blk * 2048;

    unsigned pk[32];
#pragma unroll
    for (int k = 0; k < 8; ++k) {
        int i4 = b4 + k * 256 + t;
        if (i4 < E4) {
            int4 s4 = src4[i4];
            int4 d4 = dst4[i4];
#pragma unroll
            for (int j = 0; j < 4; ++j) {
                unsigned d = (unsigned)((const int*)&d4)[j];
                unsigned s = (unsigned)((const int*)&s4)[j] & 31u;
                pk[k * 4 + j] = (d << 5) | s;  // bucket = pk>>13
            }
        } else {
#pragma unroll
            for (int j = 0; j < 4; ++j) pk[k * 4 + j] = 0xFFFFFFFFu;
        }
    }

    // ---- weight prep on blocks 0..27, wave 0 only ----
    if (blk < 28 && t < 64) {
        const float* W;
        int fi;
        if (blk < 4) {
            W = w0a; fi = blk;
        } else if (blk < 12) {
            W = w0b; fi = blk - 4;
        } else if (blk < 20) {
            W = w1a; fi = blk - 12;
        } else {
            W = w1b; fi = blk - 20;
        }
        int kt = fi >> 2, ct = fi & 3;
        int q = t >> 4, r = t & 15;
        half8 hi;
#pragma unroll
        for (int j = 0; j < 8; ++j) {
            float w = W[(kt * 32 + q * 8 + j) * 64 + ct * 16 + r];
            hi[j] = (_Float16)w;
        }
        *(half8*)(wf + blk * 1024 + t * 8) = hi;
    }

    // ---- two staging passes over bucket halves ----
    for (int p = 0; p < 2; ++p) {
        cur[t] = 0;
        cur[256 + t] = 0;
        __syncthreads();
#pragma unroll
        for (int k = 0; k < 32; ++k) {
            unsigned v = pk[k];
            if (v == 0xFFFFFFFFu) continue;
            unsigned bkt = v >> 13;
            if ((int)(bkt >> 9) != p) continue;
            unsigned lb = bkt & 511u;
            unsigned slot = atomicAdd(&cur[lb], 1u);
            if (slot < 31u)
                segL[lb * 32 + 1 + slot] = (unsigned short)(v & 0x1FFFu);
        }
        __syncthreads();
        // counts into slot 0, coalesced burst out
#pragma unroll
        for (int j = 0; j < 2; ++j) {
            int lb = j * 256 + t;
            segL[lb * 32] = (unsigned short)min(cur[lb], 31u);
            const uint4* ls = (const uint4*)&segL[lb * 32];
            uint4 u0 = ls[0], u1 = ls[1], u2 = ls[2], u3 = ls[3];
            uint4* gs = (uint4*)(packed + (size_t)blk * 32768 +
                                 (size_t)(p * BPP + lb) * 32);
            gs[0] = u0;
            gs[1] = u1;
            gs[2] = u2;
            gs[3] = u3;
        }
        __syncthreads();
    }
}

// ---------------------------------------------------------------------------
// K2: fused model. One block (4 waves) per 8-graph bucket. Thread tid reads
// partition-block tid's segment for this bucket (32B, + conditional 32B when
// count>15; count embedded in slot 0). Counts -> nibble array overlaying
// wave 3's Act tail (reg-consumed, barrier-fenced). LDS 36864B -> 4 blk/CU.
// R12: f16-hi weights only (no lo plane) — 132 MFMA/wave, half the weight
// loads; absmax budget 2x margin vs threshold.
// ---------------------------------------------------------------------------
__global__ __launch_bounds__(256, 4) void seal_fused(
    const int* __restrict__ labels, const float* __restrict__ emb,
    const float* __restrict__ b0a, const float* __restrict__ b0b,
    const float* __restrict__ b1a, const float* __restrict__ b1b,
    const float* __restrict__ ws1, const float* __restrict__ bs1,
    const float* __restrict__ ws2, const float* __restrict__ bs2,
    const unsigned short* __restrict__ pkd, int nPart,
    const _Float16* __restrict__ wf, float* __restrict__ out) {
    const int b = blockIdx.x;  // bucket: graphs b*8 .. b*8+7
    const int tid = threadIdx.x;
    const int wid = tid >> 6, l = tid & 63;
    const int q = l >> 4, r = l & 15;

    __shared__ __align__(16) _Float16 ActAll[4][64 * 72];  // 36864 B total
    unsigned* cntL = (unsigned*)((char*)ActAll + 32256);   // overlay, 4 KB

#pragma unroll
    for (int i = 0; i < 4; ++i) cntL[i * 256 + tid] = 0;
    __syncthreads();

    _Float16* Act = ActAll[wid];
    const int g0 = b * 8 + wid * 2;

    // ---- count build from embedded-count segments ----
    if (tid < nPart) {
        const uint4* seg4 =
            (const uint4*)(pkd + (size_t)tid * 32768 + (size_t)b * 32);
        uint4 v0 = seg4[0], v1 = seg4[1];
        unsigned w01[8] = {v0.x, v0.y, v0.z, v0.w, v1.x, v1.y, v1.z, v1.w};
        unsigned nf = w01[0] & 0xFFFFu;  // slot 0 = count (<=31 by writer)
#pragma unroll
        for (int i = 1; i <= 15; ++i) {
            if ((unsigned)i <= nf) {
                unsigned pk = (w01[i >> 1] >> ((i & 1) * 16)) & 0xFFFFu;
                atomicAdd(&cntL[((pk >> 10) & 7u) * 128 +
                                ((pk >> 5) & 31u) * 4 + ((pk & 31u) >> 3)],
                          1u << (4 * (pk & 7u)));
            }
        }
        if (nf > 15u) {
            uint4 v2 = seg4[2], v3 = seg4[3];
            unsigned w23[8] = {v2.x, v2.y, v2.z, v2.w,
                               v3.x, v3.y, v3.z, v3.w};
#pragma unroll
            for (int i = 16; i <= 31; ++i) {
                if ((unsigned)i <= nf) {
                    unsigned pk =
                        (w23[(i - 16) >> 1] >> ((i & 1) * 16)) & 0xFFFFu;
                    atomicAdd(&cntL[((pk >> 10) & 7u) * 128 +
                                    ((pk >> 5) & 31u) * 4 + ((pk & 31u) >> 3)],
                              1u << (4 * (pk & 7u)));
                }
            }
        }
    }

    // ---- embedding -> FM0 [f][n], bytes [0,4592) of wave buffer only ----
    {
        int p = l & 31, fh = l >> 5;
        const int* lp = labels + g0 * NPG + 2 * p;
        int lab0 = min(max(lp[0], 0), 50);
        int lab1 = min(max(lp[1], 0), 50);
        float m0 = (lab0 != 0) ? 1.f : 0.f;
        float m1 = (lab1 != 0) ? 1.f : 0.f;
        const float* e0 = emb + lab0 * 32;
        const float* e1 = emb + lab1 * 32;
        half2v* A2 = (half2v*)Act;
#pragma unroll
        for (int j = 0; j < 16; ++j) {
            int f = fh * 16 + j;
            half2v v = {(_Float16)(e0[f] * m0), (_Float16)(e1[f] * m1)};
            A2[f * 36 + p] = v;
        }
    }
    __syncthreads();  // counts complete

    // ---- Cn^T B-frags from cntL (reg-consume), then fence before stores ----
    half8 cB[4];
#pragma unroll
    for (int ct = 0; ct < 4; ++ct) {
        int gg = wid * 2 + (ct >> 1);
        int d = (ct & 1) * 16 + r;
        unsigned c = cntL[gg * 128 + d * 4 + q];
        half8 f;
#pragma unroll
        for (int j = 0; j < 8; ++j) {
            int s = q * 8 + j;
            f[j] = (_Float16)((float)((c >> (4 * j)) & 15u) +
                              (s == d ? 1.f : 0.f));
        }
        cB[ct] = f;
    }
    __syncthreads();  // all waves hold cB; tail region now writable

    f32x4 acc[4][4];
    const f32x4 z4 = {0.f, 0.f, 0.f, 0.f};

    // ---- agg0: C[f32][d64] = H0^T @ Cn^T -> store RM0 [node][f32] ----
    {
        half8 aF[2][2];
#pragma unroll
        for (int mt = 0; mt < 2; ++mt)
#pragma unroll
            for (int g = 0; g < 2; ++g)
                aF[mt][g] =
                    *(const half8*)&Act[(mt * 16 + r) * 72 + g * 32 + q * 8];
#pragma unroll
        for (int mt = 0; mt < 2; ++mt)
#pragma unroll
            for (int ct = 0; ct < 4; ++ct)
                acc[mt][ct] = MFMA16(aF[mt][ct >> 1], cB[ct], z4);
#pragma unroll
        for (int mt = 0; mt < 2; ++mt)
#pragma unroll
            for (int ct = 0; ct < 4; ++ct) {
                half4v p;
#pragma unroll
                for (int i = 0; i < 4; ++i) p[i] = (_Float16)acc[mt][ct][i];
                *(half4v*)&Act[(ct * 16 + r) * 72 + mt * 16 + q * 4] = p;
            }
    }

    // ---- MLP0a: C[outf][node] = W0a^T @ act -> store RM1 [node][outf] ----
    {
        half8 bf[4];
#pragma unroll
        for (int ct = 0; ct < 4; ++ct)
            bf[ct] = *(const half8*)&Act[(ct * 16 + r) * 72 + q * 8];
        f32x4 b4[4];
#pragma unroll
        for (int mt = 0; mt < 4; ++mt)
            b4[mt] = *(const f32x4*)&b0a[mt * 16 + q * 4];
#pragma unroll
        for (int mt = 0; mt < 4; ++mt) {
            const _Float16* base = wf + (0 + mt) * 1024;
            half8 whi = *(const half8*)(base + l * 8);
#pragma unroll
            for (int ct = 0; ct < 4; ++ct) {
                f32x4 a = b4[mt];
                a = MFMA16(whi, bf[ct], a);
                acc[mt][ct] = a;
            }
        }
#pragma unroll
        for (int mt = 0; mt < 4; ++mt)
#pragma unroll
            for (int ct = 0; ct < 4; ++ct) {
                half4v p;
#pragma unroll
                for (int i = 0; i < 4; ++i)
                    p[i] = (_Float16)fmaxf(acc[mt][ct][i], 0.f);
                *(half4v*)&Act[(ct * 16 + r) * 72 + mt * 16 + q * 4] = p;
            }
    }

    // ---- MLP0b: C[node][outf2] = act @ W0b -> store FM1 [outf2][node] ----
    {
        half8 aA[4][2];
#pragma unroll
        for (int mt = 0; mt < 4; ++mt)
#pragma unroll
            for (int kt = 0; kt < 2; ++kt)
                aA[mt][kt] =
                    *(const half8*)&Act[(mt * 16 + r) * 72 + kt * 32 + q * 8];
#pragma unroll
        for (int ct = 0; ct < 4; ++ct) {
            float bb = b0b[ct * 16 + r];
            f32x4 a[4] = {{bb, bb, bb, bb}, {bb, bb, bb, bb},
                          {bb, bb, bb, bb}, {bb, bb, bb, bb}};
#pragma unroll
            for (int kt = 0; kt < 2; ++kt) {
                const _Float16* base = wf + (4 + kt * 4 + ct) * 1024;
                half8 whi = *(const half8*)(base + l * 8);
#pragma unroll
                for (int mt = 0; mt < 4; ++mt)
                    a[mt] = MFMA16(aA[mt][kt], whi, a[mt]);
            }
#pragma unroll
            for (int mt = 0; mt < 4; ++mt) acc[mt][ct] = a[mt];
        }
#pragma unroll
        for (int mt = 0; mt < 4; ++mt)
#pragma unroll
            for (int ct = 0; ct < 4; ++ct) {
                half4v p;
#pragma unroll
                for (int i = 0; i < 4; ++i)
                    p[i] = (_Float16)fmaxf(acc[mt][ct][i], 0.f);
                *(half4v*)&Act[(ct * 16 + r) * 72 + mt * 16 + q * 4] = p;
            }
    }

    // ---- agg1: C[f64][d64] = H1^T @ Cn^T -> store RM2 [node][f64] ----
    {
        half8 aF[4][2];
#pragma unroll
        for (int mt = 0; mt < 4; ++mt)
#pragma unroll
            for (int g = 0; g < 2; ++g)
                aF[mt][g] =
                    *(const half8*)&Act[(mt * 16 + r) * 72 + g * 32 + q * 8];
#pragma unroll
        for (int mt = 0; mt < 4; ++mt)
#pragma unroll
            for (int ct = 0; ct < 4; ++ct)
                acc[mt][ct] = MFMA16(aF[mt][ct >> 1], cB[ct], z4);
#pragma unroll
        for (int mt = 0; mt < 4; ++mt)
#pragma unroll
            for (int ct = 0; ct < 4; ++ct) {
                half4v p;
#pragma unroll
                for (int i = 0; i < 4; ++i) p[i] = (_Float16)acc[mt][ct][i];
                *(half4v*)&Act[(ct * 16 + r) * 72 + mt * 16 + q * 4] = p;
            }
    }

    // ---- MLP1a: C[outf][node] = W1a^T @ act -> store RM3 [node][outf] ----
    {
        half8 bf[4][2];
#pragma unroll
        for (int ct = 0; ct < 4; ++ct)
#pragma unroll
            for (int kt = 0; kt < 2; ++kt)
                bf[ct][kt] =
                    *(const half8*)&Act[(ct * 16 + r) * 72 + kt * 32 + q * 8];
        f32x4 b4[4];
#pragma unroll
        for (int mt = 0; mt < 4; ++mt)
            b4[mt] = *(const f32x4*)&b1a[mt * 16 + q * 4];
#pragma unroll
        for (int mt = 0; mt < 4; ++mt) {
            f32x4 a[4] = {b4[mt], b4[mt], b4[mt], b4[mt]};
#pragma unroll
            for (int kt = 0; kt < 2; ++kt) {
                const _Float16* base = wf + (12 + kt * 4 + mt) * 1024;
                half8 whi = *(const half8*)(base + l * 8);
#pragma unroll
                for (int ct = 0; ct < 4; ++ct)
                    a[ct] = MFMA16(whi, bf[ct][kt], a[ct]);
            }
#pragma unroll
            for (int ct = 0; ct < 4; ++ct) acc[mt][ct] = a[ct];
        }
#pragma unroll
        for (int mt = 0; mt < 4; ++mt)
#pragma unroll
            for (int ct = 0; ct < 4; ++ct) {
                half4v p;
#pragma unroll
                for (int i = 0; i < 4; ++i)
                    p[i] = (_Float16)fmaxf(acc[mt][ct][i], 0.f);
                *(half4v*)&Act[(ct * 16 + r) * 72 + mt * 16 + q * 4] = p;
            }
    }

    // ---- MLP1b: C[node][outf] = act @ W1b; relu + per-graph mean pool ----
    float ps[2][4];
    {
        half8 aA[4][2];
#pragma unroll
        for (int mt = 0; mt < 4; ++mt)
#pragma unroll
            for (int kt = 0; kt < 2; ++kt)
                aA[mt][kt] =
                    *(const half8*)&Act[(mt * 16 + r) * 72 + kt * 32 + q * 8];
#pragma unroll
        for (int ct = 0; ct < 4; ++ct) {
            float bb = b1b[ct * 16 + r];
            f32x4 a[4] = {{bb, bb, bb, bb}, {bb, bb, bb, bb},
                          {bb, bb, bb, bb}, {bb, bb, bb, bb}};
#pragma unroll
            for (int kt = 0; kt < 2; ++kt) {
                const _Float16* base = wf + (20 + kt * 4 + ct) * 1024;
                half8 whi = *(const half8*)(base + l * 8);
#pragma unroll
                for (int mt = 0; mt < 4; ++mt)
                    a[mt] = MFMA16(aA[mt][kt], whi, a[mt]);
            }
#pragma unroll
            for (int gi = 0; gi < 2; ++gi) {
                float s = 0.f;
#pragma unroll
                for (int m2 = 0; m2 < 2; ++m2)
#pragma unroll
                    for (int i = 0; i < 4; ++i)
                        s += fmaxf(a[gi * 2 + m2][i], 0.f);
                ps[gi][ct] = s;
            }
        }
    }
#pragma unroll
    for (int gi = 0; gi < 2; ++gi)
#pragma unroll
        for (int ct = 0; ct < 4; ++ct) {
            ps[gi][ct] += __shfl_xor(ps[gi][ct], 16, 64);
            ps[gi][ct] += __shfl_xor(ps[gi][ct], 32, 64);
        }
    float* F = (float*)Act;
    if (l < 16) {
#pragma unroll
        for (int gi = 0; gi < 2; ++gi)
#pragma unroll
            for (int ct = 0; ct < 4; ++ct)
                F[gi * 64 + ct * 16 + l] = ps[gi][ct] * (1.f / 32.f);
    }

    // ---- scorer: relu(hg @ ws1 + bs1) @ ws2 + bs2 (fp32, both graphs) ----
    float a0 = bs1[l], a1 = a0;
#pragma unroll
    for (int kq = 0; kq < 16; ++kq) {
        f32x4 f0 = *(const f32x4*)&F[kq * 4];
        f32x4 f1 = *(const f32x4*)&F[64 + kq * 4];
#pragma unroll
        for (int j = 0; j < 4; ++j) {
            float wv = ws1[(kq * 4 + j) * 64 + l];
            a0 = fmaf(f0[j], wv, a0);
            a1 = fmaf(f1[j], wv, a1);
        }
    }
    float w2 = ws2[l];
    float p0 = fmaxf(a0, 0.f) * w2;
    float p1 = fmaxf(a1, 0.f) * w2;
#pragma unroll
    for (int off = 32; off > 0; off >>= 1) {
        p0 += __shfl_xor(p0, off, 64);
        p1 += __shfl_xor(p1, off, 64);
    }
    if (l == 0) {
        float bb = bs2[0];
        out[g0] = p0 + bb;
        out[g0 + 1] = p1 + bb;
    }
}

// ---------------------------------------------------------------------------
extern "C" void kernel_launch(void* const* d_in, const int* in_sizes, int n_in,
                              void* d_out, int out_size, void* d_ws,
                              size_t ws_size, hipStream_t stream) {
    const int* labels = (const int*)d_in[0];
    const int* src = (const int*)d_in[1];
    const int* dst = (const int*)d_in[2];
    const float* emb = (const float*)d_in[4];
    const float* w0a = (const float*)d_in[5];
    const float* b0a = (const float*)d_in[6];
    const float* w0b = (const float*)d_in[7];
    const float* b0b = (const float*)d_in[8];
    const float* w1a = (const float*)d_in[9];
    const float* b1a = (const float*)d_in[10];
    const float* w1b = (const float*)d_in[11];
    const float* b1b = (const float*)d_in[12];
    const float* ws1 = (const float*)d_in[13];
    const float* bs1 = (const float*)d_in[14];
    const float* ws2 = (const float*)d_in[15];
    const float* bs2 = (const float*)d_in[16];
    float* out = (float*)d_out;

    const int E = in_sizes[1];  // 2097152 edges
    const int Gn = out_size;    // 8192 subgraphs

    // ws layout: wf (57344 B, pad to 64 KB) | packed (nPart * 64 KB)
    _Float16* wf = (_Float16*)d_ws;
    unsigned short* packed = (unsigned short*)((char*)d_ws + 65536);

    const int E4 = E / 4;
    const int nPart = (E4 + 2047) / 2048;  // 256 for E=2M
    part_prep<<<nPart, 256, 0, stream>>>((const int4*)src, (const int4*)dst,
                                         E4, packed, w0a, w0b, w1a, w1b, wf);
    seal_fused<<<Gn / 8, 256, 0, stream>>>(labels, emb, b0a, b0b, b1a, b1b,
                                           ws1, bs1, ws2, bs2, packed, nPart,
                                           wf, out);
}

// Round 14
// 46.919 us; speedup vs baseline: 1.1088x; 1.0112x over previous
//
#include <hip/hip_runtime.h>

#define NPG 32
#define BUCKETS 1024  // 8 graphs per bucket
#define BPP 512       // buckets per staging pass

typedef _Float16 half8 __attribute__((ext_vector_type(8)));
typedef _Float16 half4v __attribute__((ext_vector_type(4)));
typedef _Float16 half2v __attribute__((ext_vector_type(2)));
typedef float f32x4 __attribute__((ext_vector_type(4)));

#define MFMA16(a, b, c) __builtin_amdgcn_mfma_f32_16x16x32_f16(a, b, c, 0, 0, 0)

// ---------------------------------------------------------------------------
// K1: partition 8192 edges/block into per-(block,bucket) 64B segments, staged
// in LDS (2 passes x 512 buckets), written coalesced. Segment: slot0=count,
// slots 1..31 = edges ((g&7)<<10|d<<5|s). Block-major global layout; each
// segment read exactly once by K2. Blocks 0..27 wave 0 prep f16-hi weight
// frags, COMPACT layout: 512 halfs (1KB) per frag, 28KB total -> L1-fit.
// ---------------------------------------------------------------------------
__global__ __launch_bounds__(256) void part_prep(
    const int4* __restrict__ src4, const int4* __restrict__ dst4, int E4,
    unsigned short* __restrict__ packed,
    const float* __restrict__ w0a, const float* __restrict__ w0b,
    const float* __restrict__ w1a, const float* __restrict__ w1b,
    _Float16* __restrict__ wf) {
    __shared__ unsigned cur[BPP];              // 2 KB
    __shared__ unsigned short segL[BPP * 32];  // 32 KB
    const int t = threadIdx.x;
    const int blk = blockIdx.x;
    const int b4 = blk * 2048;

    unsigned pk[32];
#pragma unroll
    for (int k = 0; k < 8; ++k) {
        int i4 = b4 + k * 256 + t;
        if (i4 < E4) {
            int4 s4 = src4[i4];
            int4 d4 = dst4[i4];
#pragma unroll
            for (int j = 0; j < 4; ++j) {
                unsigned d = (unsigned)((const int*)&d4)[j];
                unsigned s = (unsigned)((const int*)&s4)[j] & 31u;
                pk[k * 4 + j] = (d << 5) | s;  // bucket = pk>>13
            }
        } else {
#pragma unroll
            for (int j = 0; j < 4; ++j) pk[k * 4 + j] = 0xFFFFFFFFu;
        }
    }

    // ---- weight prep on blocks 0..27, wave 0 (compact 1KB/frag) ----
    if (blk < 28 && t < 64) {
        const float* W;
        int fi;
        if (blk < 4) {
            W = w0a; fi = blk;
        } else if (blk < 12) {
            W = w0b; fi = blk - 4;
        } else if (blk < 20) {
            W = w1a; fi = blk - 12;
        } else {
            W = w1b; fi = blk - 20;
        }
        int kt = fi >> 2, ct = fi & 3;
        int q = t >> 4, r = t & 15;
        half8 hi;
#pragma unroll
        for (int j = 0; j < 8; ++j)
            hi[j] = (_Float16)W[(kt * 32 + q * 8 + j) * 64 + ct * 16 + r];
        *(half8*)(wf + blk * 512 + t * 8) = hi;
    }

    // ---- two staging passes over bucket halves ----
    for (int p = 0; p < 2; ++p) {
        cur[t] = 0;
        cur[256 + t] = 0;
        __syncthreads();
#pragma unroll
        for (int k = 0; k < 32; ++k) {
            unsigned v = pk[k];
            if (v == 0xFFFFFFFFu) continue;
            unsigned bkt = v >> 13;
            if ((int)(bkt >> 9) != p) continue;
            unsigned lb = bkt & 511u;
            unsigned slot = atomicAdd(&cur[lb], 1u);
            if (slot < 31u)
                segL[lb * 32 + 1 + slot] = (unsigned short)(v & 0x1FFFu);
        }
        __syncthreads();
#pragma unroll
        for (int j = 0; j < 2; ++j) {
            int lb = j * 256 + t;
            segL[lb * 32] = (unsigned short)min(cur[lb], 31u);
            const uint4* ls = (const uint4*)&segL[lb * 32];
            uint4 u0 = ls[0], u1 = ls[1], u2 = ls[2], u3 = ls[3];
            uint4* gs = (uint4*)(packed + (size_t)blk * 32768 +
                                 (size_t)(p * BPP + lb) * 32);
            gs[0] = u0;
            gs[1] = u1;
            gs[2] = u2;
            gs[3] = u3;
        }
        __syncthreads();
    }
}

// ---------------------------------------------------------------------------
// K2: fused model. One block (4 waves) per 8-graph bucket. Segment loads
// issued BEFORE the cntL zero+barrier (latency hidden). Counts -> nibble
// array overlaying wave 3's Act tail (reg-consumed, barrier-fenced).
// f16-hi weights from the compact 28KB L1-resident wf. LDS 36864B, 4 blk/CU.
// ---------------------------------------------------------------------------
__global__ __launch_bounds__(256, 4) void seal_fused(
    const int* __restrict__ labels, const float* __restrict__ emb,
    const float* __restrict__ b0a, const float* __restrict__ b0b,
    const float* __restrict__ b1a, const float* __restrict__ b1b,
    const float* __restrict__ ws1, const float* __restrict__ bs1,
    const float* __restrict__ ws2, const float* __restrict__ bs2,
    const unsigned short* __restrict__ pkd, int nPart,
    const _Float16* __restrict__ wf, float* __restrict__ out) {
    const int b = blockIdx.x;  // bucket: graphs b*8 .. b*8+7
    const int tid = threadIdx.x;
    const int wid = tid >> 6, l = tid & 63;
    const int q = l >> 4, r = l & 15;

    __shared__ __align__(16) _Float16 ActAll[4][64 * 72];  // 36864 B total
    unsigned* cntL = (unsigned*)((char*)ActAll + 32256);   // overlay, 4 KB

    // issue segment loads early (latency hidden under zero+barrier)
    uint4 v0, v1;
    const uint4* seg4 = (const uint4*)(pkd + (size_t)tid * 32768 +
                                       (size_t)b * 32);
    if (tid < nPart) {
        v0 = seg4[0];
        v1 = seg4[1];
    }

#pragma unroll
    for (int i = 0; i < 4; ++i) cntL[i * 256 + tid] = 0;
    __syncthreads();

    _Float16* Act = ActAll[wid];
    const int g0 = b * 8 + wid * 2;

    // ---- count build from embedded-count segments ----
    if (tid < nPart) {
        unsigned w01[8] = {v0.x, v0.y, v0.z, v0.w, v1.x, v1.y, v1.z, v1.w};
        unsigned nf = w01[0] & 0xFFFFu;  // slot 0 = count (<=31 by writer)
#pragma unroll
        for (int i = 1; i <= 15; ++i) {
            if ((unsigned)i <= nf) {
                unsigned pk = (w01[i >> 1] >> ((i & 1) * 16)) & 0xFFFFu;
                atomicAdd(&cntL[((pk >> 10) & 7u) * 128 +
                                ((pk >> 5) & 31u) * 4 + ((pk & 31u) >> 3)],
                          1u << (4 * (pk & 7u)));
            }
        }
        if (nf > 15u) {
            uint4 v2 = seg4[2], v3 = seg4[3];
            unsigned w23[8] = {v2.x, v2.y, v2.z, v2.w,
                               v3.x, v3.y, v3.z, v3.w};
#pragma unroll
            for (int i = 16; i <= 31; ++i) {
                if ((unsigned)i <= nf) {
                    unsigned pk =
                        (w23[(i - 16) >> 1] >> ((i & 1) * 16)) & 0xFFFFu;
                    atomicAdd(&cntL[((pk >> 10) & 7u) * 128 +
                                    ((pk >> 5) & 31u) * 4 + ((pk & 31u) >> 3)],
                              1u << (4 * (pk & 7u)));
                }
            }
        }
    }

    // ---- embedding -> FM0 [f][n], bytes [0,4592) of wave buffer only ----
    {
        int p = l & 31, fh = l >> 5;
        const int* lp = labels + g0 * NPG + 2 * p;
        int lab0 = min(max(lp[0], 0), 50);
        int lab1 = min(max(lp[1], 0), 50);
        float m0 = (lab0 != 0) ? 1.f : 0.f;
        float m1 = (lab1 != 0) ? 1.f : 0.f;
        const float* e0 = emb + lab0 * 32;
        const float* e1 = emb + lab1 * 32;
        half2v* A2 = (half2v*)Act;
#pragma unroll
        for (int j = 0; j < 16; ++j) {
            int f = fh * 16 + j;
            half2v v = {(_Float16)(e0[f] * m0), (_Float16)(e1[f] * m1)};
            A2[f * 36 + p] = v;
        }
    }
    __syncthreads();  // counts complete

    // ---- Cn^T B-frags from cntL (reg-consume), then fence before stores ----
    half8 cB[4];
#pragma unroll
    for (int ct = 0; ct < 4; ++ct) {
        int gg = wid * 2 + (ct >> 1);
        int d = (ct & 1) * 16 + r;
        unsigned c = cntL[gg * 128 + d * 4 + q];
        half8 f;
#pragma unroll
        for (int j = 0; j < 8; ++j) {
            int s = q * 8 + j;
            f[j] = (_Float16)((float)((c >> (4 * j)) & 15u) +
                              (s == d ? 1.f : 0.f));
        }
        cB[ct] = f;
    }
    __syncthreads();  // all waves hold cB; tail region now writable

    f32x4 acc[4][4];
    const f32x4 z4 = {0.f, 0.f, 0.f, 0.f};

    // ---- agg0: C[f32][d64] = H0^T @ Cn^T -> store RM0 [node][f32] ----
    {
        half8 aF[2][2];
#pragma unroll
        for (int mt = 0; mt < 2; ++mt)
#pragma unroll
            for (int g = 0; g < 2; ++g)
                aF[mt][g] =
                    *(const half8*)&Act[(mt * 16 + r) * 72 + g * 32 + q * 8];
#pragma unroll
        for (int mt = 0; mt < 2; ++mt)
#pragma unroll
            for (int ct = 0; ct < 4; ++ct)
                acc[mt][ct] = MFMA16(aF[mt][ct >> 1], cB[ct], z4);
#pragma unroll
        for (int mt = 0; mt < 2; ++mt)
#pragma unroll
            for (int ct = 0; ct < 4; ++ct) {
                half4v p;
#pragma unroll
                for (int i = 0; i < 4; ++i) p[i] = (_Float16)acc[mt][ct][i];
                *(half4v*)&Act[(ct * 16 + r) * 72 + mt * 16 + q * 4] = p;
            }
    }

    // ---- MLP0a: C[outf][node] = W0a^T @ act -> store RM1 [node][outf] ----
    {
        half8 bf[4];
#pragma unroll
        for (int ct = 0; ct < 4; ++ct)
            bf[ct] = *(const half8*)&Act[(ct * 16 + r) * 72 + q * 8];
        f32x4 b4[4];
#pragma unroll
        for (int mt = 0; mt < 4; ++mt)
            b4[mt] = *(const f32x4*)&b0a[mt * 16 + q * 4];
#pragma unroll
        for (int mt = 0; mt < 4; ++mt) {
            half8 whi = *(const half8*)(wf + (0 + mt) * 512 + l * 8);
#pragma unroll
            for (int ct = 0; ct < 4; ++ct) {
                f32x4 a = b4[mt];
                a = MFMA16(whi, bf[ct], a);
                acc[mt][ct] = a;
            }
        }
#pragma unroll
        for (int mt = 0; mt < 4; ++mt)
#pragma unroll
            for (int ct = 0; ct < 4; ++ct) {
                half4v p;
#pragma unroll
                for (int i = 0; i < 4; ++i)
                    p[i] = (_Float16)fmaxf(acc[mt][ct][i], 0.f);
                *(half4v*)&Act[(ct * 16 + r) * 72 + mt * 16 + q * 4] = p;
            }
    }

    // ---- MLP0b: C[node][outf2] = act @ W0b -> store FM1 [outf2][node] ----
    {
        half8 aA[4][2];
#pragma unroll
        for (int mt = 0; mt < 4; ++mt)
#pragma unroll
            for (int kt = 0; kt < 2; ++kt)
                aA[mt][kt] =
                    *(const half8*)&Act[(mt * 16 + r) * 72 + kt * 32 + q * 8];
#pragma unroll
        for (int ct = 0; ct < 4; ++ct) {
            float bb = b0b[ct * 16 + r];
            f32x4 a[4] = {{bb, bb, bb, bb}, {bb, bb, bb, bb},
                          {bb, bb, bb, bb}, {bb, bb, bb, bb}};
#pragma unroll
            for (int kt = 0; kt < 2; ++kt) {
                half8 whi =
                    *(const half8*)(wf + (4 + kt * 4 + ct) * 512 + l * 8);
#pragma unroll
                for (int mt = 0; mt < 4; ++mt)
                    a[mt] = MFMA16(aA[mt][kt], whi, a[mt]);
            }
#pragma unroll
            for (int mt = 0; mt < 4; ++mt) acc[mt][ct] = a[mt];
        }
#pragma unroll
        for (int mt = 0; mt < 4; ++mt)
#pragma unroll
            for (int ct = 0; ct < 4; ++ct) {
                half4v p;
#pragma unroll
                for (int i = 0; i < 4; ++i)
                    p[i] = (_Float16)fmaxf(acc[mt][ct][i], 0.f);
                *(half4v*)&Act[(ct * 16 + r) * 72 + mt * 16 + q * 4] = p;
            }
    }

    // ---- agg1: C[f64][d64] = H1^T @ Cn^T -> store RM2 [node][f64] ----
    {
        half8 aF[4][2];
#pragma unroll
        for (int mt = 0; mt < 4; ++mt)
#pragma unroll
            for (int g = 0; g < 2; ++g)
                aF[mt][g] =
                    *(const half8*)&Act[(mt * 16 + r) * 72 + g * 32 + q * 8];
#pragma unroll
        for (int mt = 0; mt < 4; ++mt)
#pragma unroll
            for (int ct = 0; ct < 4; ++ct)
                acc[mt][ct] = MFMA16(aF[mt][ct >> 1], cB[ct], z4);
#pragma unroll
        for (int mt = 0; mt < 4; ++mt)
#pragma unroll
            for (int ct = 0; ct < 4; ++ct) {
                half4v p;
#pragma unroll
                for (int i = 0; i < 4; ++i) p[i] = (_Float16)acc[mt][ct][i];
                *(half4v*)&Act[(ct * 16 + r) * 72 + mt * 16 + q * 4] = p;
            }
    }

    // ---- MLP1a: C[outf][node] = W1a^T @ act -> store RM3 [node][outf] ----
    {
        half8 bf[4][2];
#pragma unroll
        for (int ct = 0; ct < 4; ++ct)
#pragma unroll
            for (int kt = 0; kt < 2; ++kt)
                bf[ct][kt] =
                    *(const half8*)&Act[(ct * 16 + r) * 72 + kt * 32 + q * 8];
        f32x4 b4[4];
#pragma unroll
        for (int mt = 0; mt < 4; ++mt)
            b4[mt] = *(const f32x4*)&b1a[mt * 16 + q * 4];
#pragma unroll
        for (int mt = 0; mt < 4; ++mt) {
            f32x4 a[4] = {b4[mt], b4[mt], b4[mt], b4[mt]};
#pragma unroll
            for (int kt = 0; kt < 2; ++kt) {
                half8 whi =
                    *(const half8*)(wf + (12 + kt * 4 + mt) * 512 + l * 8);
#pragma unroll
                for (int ct = 0; ct < 4; ++ct)
                    a[ct] = MFMA16(whi, bf[ct][kt], a[ct]);
            }
#pragma unroll
            for (int ct = 0; ct < 4; ++ct) acc[mt][ct] = a[ct];
        }
#pragma unroll
        for (int mt = 0; mt < 4; ++mt)
#pragma unroll
            for (int ct = 0; ct < 4; ++ct) {
                half4v p;
#pragma unroll
                for (int i = 0; i < 4; ++i)
                    p[i] = (_Float16)fmaxf(acc[mt][ct][i], 0.f);
                *(half4v*)&Act[(ct * 16 + r) * 72 + mt * 16 + q * 4] = p;
            }
    }

    // ---- MLP1b: C[node][outf] = act @ W1b; relu + per-graph mean pool ----
    float ps[2][4];
    {
        half8 aA[4][2];
#pragma unroll
        for (int mt = 0; mt < 4; ++mt)
#pragma unroll
            for (int kt = 0; kt < 2; ++kt)
                aA[mt][kt] =
                    *(const half8*)&Act[(mt * 16 + r) * 72 + kt * 32 + q * 8];
#pragma unroll
        for (int ct = 0; ct < 4; ++ct) {
            float bb = b1b[ct * 16 + r];
            f32x4 a[4] = {{bb, bb, bb, bb}, {bb, bb, bb, bb},
                          {bb, bb, bb, bb}, {bb, bb, bb, bb}};
#pragma unroll
            for (int kt = 0; kt < 2; ++kt) {
                half8 whi =
                    *(const half8*)(wf + (20 + kt * 4 + ct) * 512 + l * 8);
#pragma unroll
                for (int mt = 0; mt < 4; ++mt)
                    a[mt] = MFMA16(aA[mt][kt], whi, a[mt]);
            }
#pragma unroll
            for (int gi = 0; gi < 2; ++gi) {
                float s = 0.f;
#pragma unroll
                for (int m2 = 0; m2 < 2; ++m2)
#pragma unroll
                    for (int i = 0; i < 4; ++i)
                        s += fmaxf(a[gi * 2 + m2][i], 0.f);
                ps[gi][ct] = s;
            }
        }
    }
#pragma unroll
    for (int gi = 0; gi < 2; ++gi)
#pragma unroll
        for (int ct = 0; ct < 4; ++ct) {
            ps[gi][ct] += __shfl_xor(ps[gi][ct], 16, 64);
            ps[gi][ct] += __shfl_xor(ps[gi][ct], 32, 64);
        }
    float* F = (float*)Act;
    if (l < 16) {
#pragma unroll
        for (int gi = 0; gi < 2; ++gi)
#pragma unroll
            for (int ct = 0; ct < 4; ++ct)
                F[gi * 64 + ct * 16 + l] = ps[gi][ct] * (1.f / 32.f);
    }

    // ---- scorer: relu(hg @ ws1 + bs1) @ ws2 + bs2 (fp32, both graphs) ----
    float a0 = bs1[l], a1 = a0;
#pragma unroll
    for (int kq = 0; kq < 16; ++kq) {
        f32x4 f0 = *(const f32x4*)&F[kq * 4];
        f32x4 f1 = *(const f32x4*)&F[64 + kq * 4];
#pragma unroll
        for (int j = 0; j < 4; ++j) {
            float wv = ws1[(kq * 4 + j) * 64 + l];
            a0 = fmaf(f0[j], wv, a0);
            a1 = fmaf(f1[j], wv, a1);
        }
    }
    float w2 = ws2[l];
    float p0 = fmaxf(a0, 0.f) * w2;
    float p1 = fmaxf(a1, 0.f) * w2;
#pragma unroll
    for (int off = 32; off > 0; off >>= 1) {
        p0 += __shfl_xor(p0, off, 64);
        p1 += __shfl_xor(p1, off, 64);
    }
    if (l == 0) {
        float bb = bs2[0];
        out[g0] = p0 + bb;
        out[g0 + 1] = p1 + bb;
    }
}

// ---------------------------------------------------------------------------
extern "C" void kernel_launch(void* const* d_in, const int* in_sizes, int n_in,
                              void* d_out, int out_size, void* d_ws,
                              size_t ws_size, hipStream_t stream) {
    const int* labels = (const int*)d_in[0];
    const int* src = (const int*)d_in[1];
    const int* dst = (const int*)d_in[2];
    const float* emb = (const float*)d_in[4];
    const float* w0a = (const float*)d_in[5];
    const float* b0a = (const float*)d_in[6];
    const float* w0b = (const float*)d_in[7];
    const float* b0b = (const float*)d_in[8];
    const float* w1a = (const float*)d_in[9];
    const float* b1a = (const float*)d_in[10];
    const float* w1b = (const float*)d_in[11];
    const float* b1b = (const float*)d_in[12];
    const float* ws1 = (const float*)d_in[13];
    const float* bs1 = (const float*)d_in[14];
    const float* ws2 = (const float*)d_in[15];
    const float* bs2 = (const float*)d_in[16];
    float* out = (float*)d_out;

    const int E = in_sizes[1];  // 2097152 edges
    const int Gn = out_size;    // 8192 subgraphs

    // ws layout: wf (28672 B, pad to 32 KB) | packed (nPart * 64 KB)
    _Float16* wf = (_Float16*)d_ws;
    unsigned short* packed = (unsigned short*)((char*)d_ws + 32768);

    const int E4 = E / 4;
    const int nPart = (E4 + 2047) / 2048;  // 256 for E=2M
    part_prep<<<nPart, 256, 0, stream>>>((const int4*)src, (const int4*)dst,
                                         E4, packed, w0a, w0b, w1a, w1b, wf);
    seal_fused<<<Gn / 8, 256, 0, stream>>>(labels, emb, b0a, b0b, b1a, b1b,
                                           ws1, bs1, ws2, bs2, packed, nPart,
                                           wf, out);
}